// Round 1
// baseline (693.279 us; speedup 1.0000x reference)
//
#include <hip/hip_runtime.h>
#include <hip/hip_bf16.h>

// Problem shapes (fixed by reference setup_inputs):
//   B=2048, L=50, D=64, NI=100000, NU=100000
// out = scores (B, NI) fp32 ; ws holds pooled (B, D) fp32.

#define L_SEQ 50
#define D_EMB 64
#define SHORT_LEN 10
#define LS_LEN 11
#define NEG_INF_F (-1000000000.0f)

__device__ __forceinline__ float wave_sum(float v) {
#pragma unroll
  for (int off = 32; off > 0; off >>= 1) v += __shfl_xor(v, off, 64);
  return v;
}
__device__ __forceinline__ float wave_max(float v) {
#pragma unroll
  for (int off = 32; off > 0; off >>= 1) v = fmaxf(v, __shfl_xor(v, off, 64));
  return v;
}

// One 64-thread wave per batch row. lane = output channel e (and d index).
__global__ __launch_bounds__(64) void pool_kernel(
    const int* __restrict__ seq, const int* __restrict__ user_id,
    const float* __restrict__ item_emb, const float* __restrict__ user_emb,
    const float* __restrict__ w1, const float* __restrict__ w1b, const float* __restrict__ b1,
    const float* __restrict__ w2, const float* __restrict__ w2b, const float* __restrict__ b2,
    float* __restrict__ pooled) {
  const int b = blockIdx.x;
  const int lane = threadIdx.x;  // 0..63

  __shared__ float e_lds[L_SEQ][D_EMB];   // gathered item rows
  __shared__ float ls_lds[LS_LEN][D_EMB]; // [long_term, last 10 rows]
  __shared__ float a_lds[D_EMB];          // softmax weights (reused)
  __shared__ int seq_lds[L_SEQ];

  if (lane < L_SEQ) seq_lds[lane] = seq[b * L_SEQ + lane];
  const float u = user_emb[(long)user_id[b] * D_EMB + lane];
  __syncthreads();

  // gather e rows (coalesced 256B per row)
  for (int l = 0; l < L_SEQ; ++l) {
    e_lds[l][lane] = item_emb[(long)seq_lds[l] * D_EMB + lane];
  }

  // preload w1 row for this lane (w[e][d], e = lane)
  float4 w1r[16];
#pragma unroll
  for (int k = 0; k < 16; ++k) w1r[k] = *(const float4*)&w1[lane * D_EMB + 4 * k];
  const float bias1 = w1b[lane] + b1[lane];
  __syncthreads();

  // ---- stage 1: h = relu(e @ w1^T + bias); s[l] = <h[l], u>; mask; softmax over L ----
  float s_val = 0.0f;
  for (int l = 0; l < L_SEQ; ++l) {
    float acc = bias1;
#pragma unroll
    for (int k = 0; k < 16; ++k) {
      float4 ev = *(const float4*)&e_lds[l][4 * k];  // broadcast read
      acc = fmaf(ev.x, w1r[k].x, acc);
      acc = fmaf(ev.y, w1r[k].y, acc);
      acc = fmaf(ev.z, w1r[k].z, acc);
      acc = fmaf(ev.w, w1r[k].w, acc);
    }
    acc = fmaxf(acc, 0.0f);
    float t = wave_sum(acc * u);
    if (lane == l) s_val = (seq_lds[l] == 0) ? NEG_INF_F : t;
  }
  {
    float x = (lane < L_SEQ) ? s_val : -INFINITY;
    float m = wave_max(x);
    float p = (lane < L_SEQ) ? __expf(x - m) : 0.0f;
    float ps = wave_sum(p);
    a_lds[lane] = p / ps;
  }
  __syncthreads();

  // long_term[d] = sum_l a[l] * e[l][d]
  float lt = 0.0f;
  for (int l = 0; l < L_SEQ; ++l) lt = fmaf(a_lds[l], e_lds[l][lane], lt);
  __syncthreads();

  // ---- stage 2: ls = [long_term, e[-10:]] ----
  ls_lds[0][lane] = lt;
#pragma unroll
  for (int j = 1; j < LS_LEN; ++j)
    ls_lds[j][lane] = e_lds[L_SEQ - SHORT_LEN + (j - 1)][lane];

  float4 w2r[16];
#pragma unroll
  for (int k = 0; k < 16; ++k) w2r[k] = *(const float4*)&w2[lane * D_EMB + 4 * k];
  const float bias2 = w2b[lane] + b2[lane];
  __syncthreads();

  float s2_val = 0.0f;
  for (int j = 0; j < LS_LEN; ++j) {
    float acc = bias2;
#pragma unroll
    for (int k = 0; k < 16; ++k) {
      float4 lv = *(const float4*)&ls_lds[j][4 * k];
      acc = fmaf(lv.x, w2r[k].x, acc);
      acc = fmaf(lv.y, w2r[k].y, acc);
      acc = fmaf(lv.z, w2r[k].z, acc);
      acc = fmaf(lv.w, w2r[k].w, acc);
    }
    acc = fmaxf(acc, 0.0f);
    float t = wave_sum(acc * u);
    bool msk = (j == 0) ? false : (seq_lds[L_SEQ - SHORT_LEN + (j - 1)] == 0);
    if (lane == j) s2_val = msk ? NEG_INF_F : t;
  }
  {
    float x = (lane < LS_LEN) ? s2_val : -INFINITY;
    float m = wave_max(x);
    float p = (lane < LS_LEN) ? __expf(x - m) : 0.0f;
    float ps = wave_sum(p);
    __syncthreads();  // a_lds reuse
    a_lds[lane] = p / ps;
  }
  __syncthreads();

  float po = 0.0f;
#pragma unroll
  for (int j = 0; j < LS_LEN; ++j) po = fmaf(a_lds[j], ls_lds[j][lane], po);
  pooled[(long)b * D_EMB + lane] = po;
}

// scores[b,i] = sum_d pooled[b][d] * item_emb[i][d]
// 64x64 tile per 256-thread block; both tiles stored d-major in LDS (stride 68).
__global__ __launch_bounds__(256) void scores_kernel(
    const float* __restrict__ pooled, const float* __restrict__ item_emb,
    float* __restrict__ out, int NI) {
  constexpr int STR = 68;  // 16B-aligned rows, low bank conflict
  __shared__ __align__(16) float poolT[64 * STR];  // [d][b_local]
  __shared__ __align__(16) float itemT[64 * STR];  // [d][i_local]

  const int tid = threadIdx.x;
  const int lane = tid & 63;   // = d index during load
  const int b0 = blockIdx.x * 64;
  const int i0 = blockIdx.y * 64;

  for (int r = tid >> 6; r < 64; r += 4) {  // r = local row
    poolT[lane * STR + r] = pooled[(long)(b0 + r) * D_EMB + lane];
    int i = i0 + r;
    itemT[lane * STR + r] = (i < NI) ? item_emb[(long)i * D_EMB + lane] : 0.0f;
  }
  __syncthreads();

  const int tx = tid & 15;  // i group
  const int ty = tid >> 4;  // b group
  float acc[4][4] = {};

#pragma unroll 8
  for (int d = 0; d < 64; ++d) {
    float4 pv = *(const float4*)&poolT[d * STR + ty * 4];
    float4 iv = *(const float4*)&itemT[d * STR + tx * 4];
    float pva[4] = {pv.x, pv.y, pv.z, pv.w};
    float iva[4] = {iv.x, iv.y, iv.z, iv.w};
#pragma unroll
    for (int m = 0; m < 4; ++m)
#pragma unroll
      for (int n = 0; n < 4; ++n) acc[m][n] = fmaf(pva[m], iva[n], acc[m][n]);
  }

  const int ibase = i0 + tx * 4;
  const long orow = (long)(b0 + ty * 4);
  if (i0 + 63 < NI) {
#pragma unroll
    for (int m = 0; m < 4; ++m) {
      float4 v = make_float4(acc[m][0], acc[m][1], acc[m][2], acc[m][3]);
      *(float4*)&out[(orow + m) * (long)NI + ibase] = v;
    }
  } else {
#pragma unroll
    for (int m = 0; m < 4; ++m)
#pragma unroll
      for (int n = 0; n < 4; ++n)
        if (ibase + n < NI) out[(orow + m) * (long)NI + ibase + n] = acc[m][n];
  }
}

extern "C" void kernel_launch(void* const* d_in, const int* in_sizes, int n_in,
                              void* d_out, int out_size, void* d_ws, size_t ws_size,
                              hipStream_t stream) {
  const int* seq = (const int*)d_in[0];
  const int* user_id = (const int*)d_in[1];
  const float* item_emb = (const float*)d_in[2];
  const float* user_emb = (const float*)d_in[3];
  const float* w1 = (const float*)d_in[4];
  const float* w1b = (const float*)d_in[5];
  const float* b1 = (const float*)d_in[6];
  const float* w2 = (const float*)d_in[7];
  const float* w2b = (const float*)d_in[8];
  const float* b2 = (const float*)d_in[9];
  float* out = (float*)d_out;

  const int B = in_sizes[1];              // 2048
  const int NI = in_sizes[2] / D_EMB;     // 100000

  float* pooled = (float*)d_ws;           // B * 64 floats

  pool_kernel<<<B, 64, 0, stream>>>(seq, user_id, item_emb, user_emb,
                                    w1, w1b, b1, w2, w2b, b2, pooled);

  dim3 grid(B / 64, (NI + 63) / 64);
  scores_kernel<<<grid, 256, 0, stream>>>(pooled, item_emb, out, NI);
}

// Round 2
// 312.957 us; speedup vs baseline: 2.2153x; 2.2153x over previous
//
#include <hip/hip_runtime.h>
#include <hip/hip_bf16.h>

// Problem shapes (fixed by reference setup_inputs):
//   B=2048, L=50, D=64, NI=100000, NU=100000
// out = scores (B, NI) fp32.
// ws layout (MFMA path): [item_bf16: NI*64*2][pooled_bf16: B*64*2]
// ws layout (fallback):  [pooled_f32: B*64*4]

#define L_SEQ 50
#define D_EMB 64
#define SHORT_LEN 10
#define LS_LEN 11
#define NEG_INF_F (-1000000000.0f)

typedef __bf16 bf16x8 __attribute__((ext_vector_type(8)));
typedef float f32x4 __attribute__((ext_vector_type(4)));

__device__ __forceinline__ float wave_sum(float v) {
#pragma unroll
  for (int off = 32; off > 0; off >>= 1) v += __shfl_xor(v, off, 64);
  return v;
}
__device__ __forceinline__ float wave_max(float v) {
#pragma unroll
  for (int off = 32; off > 0; off >>= 1) v = fmaxf(v, __shfl_xor(v, off, 64));
  return v;
}

// One 64-thread wave per batch row. lane = output channel e (and d index).
__global__ __launch_bounds__(64) void pool_kernel(
    const int* __restrict__ seq, const int* __restrict__ user_id,
    const float* __restrict__ item_emb, const float* __restrict__ user_emb,
    const float* __restrict__ w1, const float* __restrict__ w1b, const float* __restrict__ b1,
    const float* __restrict__ w2, const float* __restrict__ w2b, const float* __restrict__ b2,
    float* __restrict__ pooled_f32, __bf16* __restrict__ pooled_bf) {
  const int b = blockIdx.x;
  const int lane = threadIdx.x;  // 0..63

  __shared__ float e_lds[L_SEQ][D_EMB];   // gathered item rows
  __shared__ float ls_lds[LS_LEN][D_EMB]; // [long_term, last 10 rows]
  __shared__ float a_lds[D_EMB];          // softmax weights (reused)
  __shared__ int seq_lds[L_SEQ];

  if (lane < L_SEQ) seq_lds[lane] = seq[b * L_SEQ + lane];
  const float u = user_emb[(long)user_id[b] * D_EMB + lane];
  __syncthreads();

  // gather e rows (coalesced 256B per row)
  for (int l = 0; l < L_SEQ; ++l) {
    e_lds[l][lane] = item_emb[(long)seq_lds[l] * D_EMB + lane];
  }

  // preload w1 row for this lane (w[e][d], e = lane)
  float4 w1r[16];
#pragma unroll
  for (int k = 0; k < 16; ++k) w1r[k] = *(const float4*)&w1[lane * D_EMB + 4 * k];
  const float bias1 = w1b[lane] + b1[lane];
  __syncthreads();

  // ---- stage 1: h = relu(e @ w1^T + bias); s[l] = <h[l], u>; mask; softmax over L ----
  float s_val = 0.0f;
  for (int l = 0; l < L_SEQ; ++l) {
    float acc = bias1;
#pragma unroll
    for (int k = 0; k < 16; ++k) {
      float4 ev = *(const float4*)&e_lds[l][4 * k];  // broadcast read
      acc = fmaf(ev.x, w1r[k].x, acc);
      acc = fmaf(ev.y, w1r[k].y, acc);
      acc = fmaf(ev.z, w1r[k].z, acc);
      acc = fmaf(ev.w, w1r[k].w, acc);
    }
    acc = fmaxf(acc, 0.0f);
    float t = wave_sum(acc * u);
    if (lane == l) s_val = (seq_lds[l] == 0) ? NEG_INF_F : t;
  }
  {
    float x = (lane < L_SEQ) ? s_val : -INFINITY;
    float m = wave_max(x);
    float p = (lane < L_SEQ) ? __expf(x - m) : 0.0f;
    float ps = wave_sum(p);
    a_lds[lane] = p / ps;
  }
  __syncthreads();

  // long_term[d] = sum_l a[l] * e[l][d]
  float lt = 0.0f;
  for (int l = 0; l < L_SEQ; ++l) lt = fmaf(a_lds[l], e_lds[l][lane], lt);
  __syncthreads();

  // ---- stage 2: ls = [long_term, e[-10:]] ----
  ls_lds[0][lane] = lt;
#pragma unroll
  for (int j = 1; j < LS_LEN; ++j)
    ls_lds[j][lane] = e_lds[L_SEQ - SHORT_LEN + (j - 1)][lane];

  float4 w2r[16];
#pragma unroll
  for (int k = 0; k < 16; ++k) w2r[k] = *(const float4*)&w2[lane * D_EMB + 4 * k];
  const float bias2 = w2b[lane] + b2[lane];
  __syncthreads();

  float s2_val = 0.0f;
  for (int j = 0; j < LS_LEN; ++j) {
    float acc = bias2;
#pragma unroll
    for (int k = 0; k < 16; ++k) {
      float4 lv = *(const float4*)&ls_lds[j][4 * k];
      acc = fmaf(lv.x, w2r[k].x, acc);
      acc = fmaf(lv.y, w2r[k].y, acc);
      acc = fmaf(lv.z, w2r[k].z, acc);
      acc = fmaf(lv.w, w2r[k].w, acc);
    }
    acc = fmaxf(acc, 0.0f);
    float t = wave_sum(acc * u);
    bool msk = (j == 0) ? false : (seq_lds[L_SEQ - SHORT_LEN + (j - 1)] == 0);
    if (lane == j) s2_val = msk ? NEG_INF_F : t;
  }
  {
    float x = (lane < LS_LEN) ? s2_val : -INFINITY;
    float m = wave_max(x);
    float p = (lane < LS_LEN) ? __expf(x - m) : 0.0f;
    float ps = wave_sum(p);
    __syncthreads();  // a_lds reuse
    a_lds[lane] = p / ps;
  }
  __syncthreads();

  float po = 0.0f;
#pragma unroll
  for (int j = 0; j < LS_LEN; ++j) po = fmaf(a_lds[j], ls_lds[j][lane], po);
  if (pooled_f32) pooled_f32[(long)b * D_EMB + lane] = po;
  if (pooled_bf) pooled_bf[(long)b * D_EMB + lane] = (__bf16)po;
}

// fp32 -> bf16, 8 elements per thread, 16B stores.
__global__ __launch_bounds__(256) void cvt_bf16_kernel(
    const float* __restrict__ in, __bf16* __restrict__ out, int n8) {
  int i = blockIdx.x * blockDim.x + threadIdx.x;
  if (i >= n8) return;
  float4 a = ((const float4*)in)[2 * i];
  float4 b = ((const float4*)in)[2 * i + 1];
  bf16x8 v;
  v[0] = (__bf16)a.x; v[1] = (__bf16)a.y; v[2] = (__bf16)a.z; v[3] = (__bf16)a.w;
  v[4] = (__bf16)b.x; v[5] = (__bf16)b.y; v[6] = (__bf16)b.z; v[7] = (__bf16)b.w;
  ((bf16x8*)out)[i] = v;
}

// MFMA scores: each block = 64 batch rows x 512 items (32 tiles of 16),
// 4 waves; wave w takes tiles t_local = w, w+4, ... (strided).
// No LDS. A-frags (8) live in VGPRs for the block lifetime; B-frags are
// single global dwordx4 loads per tile. C/D map: col=l&15, row=4*(l>>4)+reg.
__global__ __launch_bounds__(256) void scores_mfma_kernel(
    const __bf16* __restrict__ pooled_bf,  // [B][64]
    const __bf16* __restrict__ item_bf,    // [NI][64]
    float* __restrict__ out, int NI, int n_tiles) {
  const int tid = threadIdx.x;
  const int w = tid >> 6;
  const int l = tid & 63;
  const int lr = l & 15;   // row (A) / col (B,C)
  const int lg = l >> 4;   // k-group / C row-group
  const int b0 = blockIdx.x * 64;

  // A fragments: 4 row-groups x 2 k-halves, loaded once.
  bf16x8 afrag[4][2];
#pragma unroll
  for (int g = 0; g < 4; ++g) {
    const __bf16* arow = pooled_bf + (size_t)(b0 + 16 * g + lr) * D_EMB + 8 * lg;
    afrag[g][0] = *(const bf16x8*)(arow);
    afrag[g][1] = *(const bf16x8*)(arow + 32);
  }

  const int t0 = blockIdx.y * 32;
  for (int tl = w; tl < 32; tl += 4) {
    const int t = t0 + tl;
    if (t >= n_tiles) break;  // uniform per wave
    const __bf16* brow = item_bf + (size_t)(t * 16 + lr) * D_EMB + 8 * lg;
    bf16x8 bf0 = *(const bf16x8*)(brow);
    bf16x8 bf1 = *(const bf16x8*)(brow + 32);
#pragma unroll
    for (int g = 0; g < 4; ++g) {
      f32x4 acc = {0.f, 0.f, 0.f, 0.f};
      acc = __builtin_amdgcn_mfma_f32_16x16x32_bf16(afrag[g][0], bf0, acc, 0, 0, 0);
      acc = __builtin_amdgcn_mfma_f32_16x16x32_bf16(afrag[g][1], bf1, acc, 0, 0, 0);
      float* orow = out + (size_t)(b0 + 16 * g + 4 * lg) * NI + t * 16 + lr;
#pragma unroll
      for (int r = 0; r < 4; ++r) orow[(size_t)r * NI] = acc[r];
    }
  }
}

// ---------- fallback fp32 scores (round-1 kernel), used if ws too small ----------
__global__ __launch_bounds__(256) void scores_kernel(
    const float* __restrict__ pooled, const float* __restrict__ item_emb,
    float* __restrict__ out, int NI) {
  constexpr int STR = 68;
  __shared__ __align__(16) float poolT[64 * STR];
  __shared__ __align__(16) float itemT[64 * STR];

  const int tid = threadIdx.x;
  const int lane = tid & 63;
  const int b0 = blockIdx.x * 64;
  const int i0 = blockIdx.y * 64;

  for (int r = tid >> 6; r < 64; r += 4) {
    poolT[lane * STR + r] = pooled[(long)(b0 + r) * D_EMB + lane];
    int i = i0 + r;
    itemT[lane * STR + r] = (i < NI) ? item_emb[(long)i * D_EMB + lane] : 0.0f;
  }
  __syncthreads();

  const int tx = tid & 15;
  const int ty = tid >> 4;
  float acc[4][4] = {};

#pragma unroll 8
  for (int d = 0; d < 64; ++d) {
    float4 pv = *(const float4*)&poolT[d * STR + ty * 4];
    float4 iv = *(const float4*)&itemT[d * STR + tx * 4];
    float pva[4] = {pv.x, pv.y, pv.z, pv.w};
    float iva[4] = {iv.x, iv.y, iv.z, iv.w};
#pragma unroll
    for (int m = 0; m < 4; ++m)
#pragma unroll
      for (int n = 0; n < 4; ++n) acc[m][n] = fmaf(pva[m], iva[n], acc[m][n]);
  }

  const int ibase = i0 + tx * 4;
  const long orow = (long)(b0 + ty * 4);
  if (i0 + 63 < NI) {
#pragma unroll
    for (int m = 0; m < 4; ++m) {
      float4 v = make_float4(acc[m][0], acc[m][1], acc[m][2], acc[m][3]);
      *(float4*)&out[(orow + m) * (long)NI + ibase] = v;
    }
  } else {
#pragma unroll
    for (int m = 0; m < 4; ++m)
#pragma unroll
      for (int n = 0; n < 4; ++n)
        if (ibase + n < NI) out[(orow + m) * (long)NI + ibase + n] = acc[m][n];
  }
}

extern "C" void kernel_launch(void* const* d_in, const int* in_sizes, int n_in,
                              void* d_out, int out_size, void* d_ws, size_t ws_size,
                              hipStream_t stream) {
  const int* seq = (const int*)d_in[0];
  const int* user_id = (const int*)d_in[1];
  const float* item_emb = (const float*)d_in[2];
  const float* user_emb = (const float*)d_in[3];
  const float* w1 = (const float*)d_in[4];
  const float* w1b = (const float*)d_in[5];
  const float* b1 = (const float*)d_in[6];
  const float* w2 = (const float*)d_in[7];
  const float* w2b = (const float*)d_in[8];
  const float* b2 = (const float*)d_in[9];
  float* out = (float*)d_out;

  const int B = in_sizes[1];           // 2048
  const int NI = in_sizes[2] / D_EMB;  // 100000

  const size_t item_bf_bytes = (size_t)NI * D_EMB * 2;
  const size_t pooled_bf_bytes = (size_t)B * D_EMB * 2;
  const bool mfma_ok = (ws_size >= item_bf_bytes + pooled_bf_bytes) &&
                       (NI % 16 == 0) && (B % 64 == 0) && (D_EMB == 64);

  if (mfma_ok) {
    __bf16* item_bf = (__bf16*)d_ws;
    __bf16* pooled_bf = (__bf16*)((char*)d_ws + item_bf_bytes);

    const int n8 = NI * D_EMB / 8;
    cvt_bf16_kernel<<<(n8 + 255) / 256, 256, 0, stream>>>(item_emb, item_bf, n8);

    pool_kernel<<<B, 64, 0, stream>>>(seq, user_id, item_emb, user_emb,
                                      w1, w1b, b1, w2, w2b, b2,
                                      (float*)nullptr, pooled_bf);

    const int n_tiles = NI / 16;
    dim3 grid(B / 64, (n_tiles + 31) / 32);
    scores_mfma_kernel<<<grid, 256, 0, stream>>>(pooled_bf, item_bf, out, NI, n_tiles);
  } else {
    float* pooled = (float*)d_ws;  // B * 64 floats
    pool_kernel<<<B, 64, 0, stream>>>(seq, user_id, item_emb, user_emb,
                                      w1, w1b, b1, w2, w2b, b2,
                                      pooled, (__bf16*)nullptr);
    dim3 grid(B / 64, (NI + 63) / 64);
    scores_kernel<<<grid, 256, 0, stream>>>(pooled, item_emb, out, NI);
  }
}